// Round 2
// baseline (440.768 us; speedup 1.0000x reference)
//
#include <hip/hip_runtime.h>

// Problem constants: B=32, T=4096, C=256, WINDOW=8, HEADS=4, hd=64
// Rows M = B*T = 131072. qkv col n = part*256 + h*64 + d.
// 512-thread blocks (8 waves), 64-token tile, 2 blocks/CU -> 4 waves/SIMD.

typedef __attribute__((ext_vector_type(8))) short short8;
typedef __attribute__((ext_vector_type(4))) short short4v;
typedef __attribute__((ext_vector_type(4))) float float4v;

// Packed fp32x2 -> bf16x2 (RNE) in one instruction.
__device__ inline unsigned cvtpk_bf16(float a, float b) {
  unsigned r;
  asm("v_cvt_pk_bf16_f32 %0, %1, %2" : "=v"(r) : "v"(a), "v"(b));
  return r;
}

// ---- prologue: cast weights fp32 -> bf16 into workspace ----
// dst layout: [768*256] w_qkv_bf16, then [256*256] w_proj_bf16
__global__ void __launch_bounds__(256) wconv_kernel(const float* __restrict__ wqkv,
                                                    const float* __restrict__ wproj,
                                                    short* __restrict__ dst) {
  int i = blockIdx.x * 256 + threadIdx.x;          // 65536 threads, 4 elems each
  float4 v;
  if (i < 49152) v = reinterpret_cast<const float4*>(wqkv)[i];
  else           v = reinterpret_cast<const float4*>(wproj)[i - 49152];
  reinterpret_cast<uint2*>(dst)[i] =
      make_uint2(cvtpk_bf16(v.x, v.y), cvtpk_bf16(v.z, v.w));
}

// ---- fused QKV + windowed attention + proj ----
__global__ void __launch_bounds__(512, 4) attn_kernel(
    const float* __restrict__ x,
    const short* __restrict__ wbf,      // bf16 weights from workspace
    const float* __restrict__ b_qkv,
    const float* __restrict__ b_proj,
    float* __restrict__ out) {

  // LDS: 67584 B total -> 2 blocks/CU (135168 <= 163840)
  __shared__ short sA[64 * 264];        // X tile bf16 (row-major, stride 264); later aliased as attn-out tile
  __shared__ short sQK[2 * 64 * 72];    // per-head Q,K rows [token][d], stride 72
  __shared__ short sVT[64 * 72];        // per-head V^T [d][token], stride 72
  __shared__ short sP[8 * 16 * 24];     // per-wave P tile [q][k], stride 24

  const int tid  = threadIdx.x;
  const int wv   = tid >> 6;            // wave 0..7
  const int wr   = wv & 1;              // GEMM row half: rows [wr*32, wr*32+32)
  const int wc   = wv >> 1;             // GEMM col group 0..3 (48 head-cols / 64 proj-cols)
  const int lane = tid & 63;
  const int L    = lane & 15;
  const int quad = lane >> 4;           // 0..3
  const int g    = wv & 3;              // attention token group: tokens [g*16, g*16+16)
  const int hf   = wv >> 2;             // attention d-half: dc in {hf*2, hf*2+1}
  const int bid  = blockIdx.x;
  // softmax window-select: lane's q-window ((lane>>3)&1) vs which half holds it (lane>>5)
  const bool selw = (((lane >> 5) ^ (lane >> 3)) & 1);

  const float4v fzero = {0.f, 0.f, 0.f, 0.f};

  // ---------- Phase 0: stage X tile (64x256 fp32 -> bf16 LDS) ----------
  // 8 iterations x 512 threads x 4 floats = 16384 floats = the full 64x256 tile.
  const float* xg = x + (size_t)bid * (64 * 256);
  #pragma unroll
  for (int i = 0; i < 8; ++i) {
    int idx = i * 2048 + tid * 4;
    float4 v = *reinterpret_cast<const float4*>(xg + idx);
    int row = idx >> 8;
    int col = idx & 255;
    *reinterpret_cast<uint2*>(&sA[row * 264 + col]) =
        make_uint2(cvtpk_bf16(v.x, v.y), cvtpk_bf16(v.z, v.w));
  }
  __syncthreads();

  float oreg[4][8];                     // attention output per head: [dchunk_local*4 + reg]

  #pragma unroll
  for (int h = 0; h < 4; ++h) {
    // ---------- QKV GEMM: wave computes rows [wr*32,+32) x head-local cols [wc*48,+48) ----------
    float4v acc[2][3];
    #pragma unroll
    for (int rt = 0; rt < 2; ++rt)
      #pragma unroll
      for (int ct = 0; ct < 3; ++ct) acc[rt][ct] = fzero;

    const short* wb[3];
    int s_[3], d0_[3];
    #pragma unroll
    for (int ct = 0; ct < 3; ++ct) {
      int c0 = wc * 48 + ct * 16;       // head-local col
      int s  = c0 >> 6;                 // 0=q 1=k 2=v
      int d0 = c0 & 63;
      s_[ct] = s; d0_[ct] = d0;
      int wrow0 = s * 256 + h * 64 + d0;                 // row in w_qkv
      wb[ct] = wbf + (size_t)(wrow0 + L) * 256 + quad * 8;
    }

    #pragma unroll
    for (int kk = 0; kk < 8; ++kk) {
      short8 a[2];
      #pragma unroll
      for (int rt = 0; rt < 2; ++rt)
        a[rt] = *reinterpret_cast<const short8*>(&sA[(wr * 32 + rt * 16 + L) * 264 + kk * 32 + quad * 8]);
      short8 b[3];
      #pragma unroll
      for (int ct = 0; ct < 3; ++ct)
        b[ct] = *reinterpret_cast<const short8*>(wb[ct] + kk * 32);
      #pragma unroll
      for (int rt = 0; rt < 2; ++rt)
        #pragma unroll
        for (int ct = 0; ct < 3; ++ct)
          acc[rt][ct] = __builtin_amdgcn_mfma_f32_16x16x32_bf16(a[rt], b[ct], acc[rt][ct], 0, 0, 0);
    }

    // epilogue: + bias, scatter to sQK (row-major) / sVT (transposed), packed cvt
    #pragma unroll
    for (int ct = 0; ct < 3; ++ct) {
      int s = s_[ct], d0 = d0_[ct];
      float bias = b_qkv[s * 256 + h * 64 + d0 + L];
      #pragma unroll
      for (int rt = 0; rt < 2; ++rt) {
        int row0 = wr * 32 + rt * 16 + quad * 4;         // global token row of v[0]
        float4v v = acc[rt][ct];
        unsigned u01 = cvtpk_bf16(v[0] + bias, v[1] + bias);
        unsigned u23 = cvtpk_bf16(v[2] + bias, v[3] + bias);
        if (s < 2) {
          short* dq = &sQK[s * (64 * 72) + row0 * 72 + d0 + L];
          dq[0]   = (short)u01;
          dq[72]  = (short)(u01 >> 16);
          dq[144] = (short)u23;
          dq[216] = (short)(u23 >> 16);
        } else {
          *reinterpret_cast<uint2*>(&sVT[(d0 + L) * 72 + row0]) =
              make_uint2(u01, u23);
        }
      }
    }
    __syncthreads();

    // ---------- attention: wave pair (g, hf) handles tokens [g*16,+16); hf splits PV d-chunks ----------
    // Swapped operands: mfma(K, Q) -> S^T: row = local k = quad*4+r, col = local q = L.
    float4v sacc = fzero;
    #pragma unroll
    for (int ks = 0; ks < 2; ++ks) {
      short8 qa = *reinterpret_cast<const short8*>(&sQK[(g * 16 + L) * 72 + ks * 32 + quad * 8]);
      short8 kb = *reinterpret_cast<const short8*>(&sQK[64 * 72 + (g * 16 + L) * 72 + ks * 32 + quad * 8]);
      sacc = __builtin_amdgcn_mfma_f32_16x16x32_bf16(kb, qa, sacc, 0, 0, 0);
    }

    // in-register softmax (q = L, k = quad*4+r); duplicated across the wave pair (cheap)
    float sv[4];
    #pragma unroll
    for (int r = 0; r < 4; ++r) {
      int kidx = quad * 4 + r;
      bool valid = ((kidx >> 3) == (L >> 3)) && ((kidx & 7) <= (L & 7));  // same window + causal
      sv[r] = valid ? sacc[r] * 0.125f : -1e30f;
    }
    float mx = fmaxf(fmaxf(sv[0], sv[1]), fmaxf(sv[2], sv[3]));
    mx = fmaxf(mx, __shfl_xor(mx, 16));          // combine quad pairs
    {
      float mo = __shfl_xor(mx, 32);
      if (selw) mx = mo;                          // pick this lane's q-window
    }
    float e[4];
    float sum = 0.f;
    #pragma unroll
    for (int r = 0; r < 4; ++r) { e[r] = __expf(sv[r] - mx); sum += e[r]; }
    sum += __shfl_xor(sum, 16);
    {
      float so = __shfl_xor(sum, 32);
      if (selw) sum = so;
    }
    float rs = __builtin_amdgcn_rcpf(sum);
    short* sPw = &sP[wv * (16 * 24)];             // per-wave slot: no cross-wave hazard
    *reinterpret_cast<uint2*>(&sPw[L * 24 + quad * 4]) =
        make_uint2(cvtpk_bf16(e[0] * rs, e[1] * rs), cvtpk_bf16(e[2] * rs, e[3] * rs));

    // P @ V via 16x16x32 with K zero-padded 16->32 (A=0 for quads 2,3; B token clamped)
    short8 pa = {0, 0, 0, 0, 0, 0, 0, 0};
    if (quad < 2) pa = *reinterpret_cast<const short8*>(&sPw[L * 24 + quad * 8]);
    #pragma unroll
    for (int j = 0; j < 2; ++j) {
      int dc = hf * 2 + j;
      short8 vb = *reinterpret_cast<const short8*>(
          &sVT[(dc * 16 + L) * 72 + g * 16 + (quad & 1) * 8]);
      float4v o = __builtin_amdgcn_mfma_f32_16x16x32_bf16(pa, vb, fzero, 0, 0, 0);
      #pragma unroll
      for (int r = 0; r < 4; ++r) oreg[h][j * 4 + r] = o[r];
    }
    if (h != 3) __syncthreads();   // protect sQK/sVT before next head's epilogue writes
    // (h==3: attn-out writes below touch sA only; head-3 GEMM reads of sA were fenced
    //  by this head's post-epilogue barrier; PV reads touch sVT/sP only.)
  }

  // ---------- write attention output tile into sA (X tile is dead) ----------
  #pragma unroll
  for (int h = 0; h < 4; ++h)
    #pragma unroll
    for (int j = 0; j < 2; ++j) {
      unsigned u01 = cvtpk_bf16(oreg[h][j * 4 + 0], oreg[h][j * 4 + 1]);
      unsigned u23 = cvtpk_bf16(oreg[h][j * 4 + 2], oreg[h][j * 4 + 3]);
      short* dq = &sA[(g * 16 + quad * 4) * 264 + h * 64 + (hf * 2 + j) * 16 + L];
      dq[0]       = (short)u01;
      dq[264]     = (short)(u01 >> 16);
      dq[528]     = (short)u23;
      dq[792]     = (short)(u23 >> 16);
    }
  __syncthreads();

  // ---------- proj GEMM: wave computes rows [wr*32,+32) x cols [wc*64,+64) ----------
  float4v pacc[2][4];
  #pragma unroll
  for (int rt = 0; rt < 2; ++rt)
    #pragma unroll
    for (int ct = 0; ct < 4; ++ct) pacc[rt][ct] = fzero;

  const short* wp = wbf + 768 * 256;
  const short* wpb[4];
  #pragma unroll
  for (int ct = 0; ct < 4; ++ct)
    wpb[ct] = wp + (size_t)(wc * 64 + ct * 16 + L) * 256 + quad * 8;

  #pragma unroll
  for (int kk = 0; kk < 8; ++kk) {
    short8 a[2];
    #pragma unroll
    for (int rt = 0; rt < 2; ++rt)
      a[rt] = *reinterpret_cast<const short8*>(&sA[(wr * 32 + rt * 16 + L) * 264 + kk * 32 + quad * 8]);
    short8 b[4];
    #pragma unroll
    for (int ct = 0; ct < 4; ++ct)
      b[ct] = *reinterpret_cast<const short8*>(wpb[ct] + kk * 32);
    #pragma unroll
    for (int rt = 0; rt < 2; ++rt)
      #pragma unroll
      for (int ct = 0; ct < 4; ++ct)
        pacc[rt][ct] = __builtin_amdgcn_mfma_f32_16x16x32_bf16(a[rt], b[ct], pacc[rt][ct], 0, 0, 0);
  }

  // epilogue: + bias, fp32 store
  float* og = out + (size_t)bid * (64 * 256);
  #pragma unroll
  for (int ct = 0; ct < 4; ++ct) {
    float bias = b_proj[wc * 64 + ct * 16 + L];
    #pragma unroll
    for (int rt = 0; rt < 2; ++rt)
      #pragma unroll
      for (int r = 0; r < 4; ++r)
        og[(wr * 32 + rt * 16 + quad * 4 + r) * 256 + wc * 64 + ct * 16 + L] = pacc[rt][ct][r] + bias;
  }
}

extern "C" void kernel_launch(void* const* d_in, const int* in_sizes, int n_in,
                              void* d_out, int out_size, void* d_ws, size_t ws_size,
                              hipStream_t stream) {
  const float* x      = (const float*)d_in[0];
  const float* w_qkv  = (const float*)d_in[1];
  const float* b_qkv  = (const float*)d_in[2];
  const float* w_proj = (const float*)d_in[3];
  const float* b_proj = (const float*)d_in[4];
  float* out = (float*)d_out;
  short* wbf = (short*)d_ws;                      // 524288 B of bf16 weights

  wconv_kernel<<<256, 256, 0, stream>>>(w_qkv, w_proj, wbf);
  attn_kernel<<<2048, 512, 0, stream>>>(x, wbf, b_qkv, b_proj, out);
}

// Round 5
// 438.562 us; speedup vs baseline: 1.0050x; 1.0050x over previous
//
#include <hip/hip_runtime.h>

// Problem constants: B=32, T=4096, C=256, WINDOW=8, HEADS=4, hd=64
// Rows M = B*T = 131072. 32-token tiles -> 4096 blocks, 256 threads (4 waves).
// Mechanical halving of the verified 64-token kernel: LDS 36864 B -> 4 blocks/CU.

typedef __attribute__((ext_vector_type(8))) short short8;
typedef __attribute__((ext_vector_type(4))) short short4v;
typedef __attribute__((ext_vector_type(4))) float float4v;

// Packed fp32x2 -> bf16x2 (RNE) in one instruction.
__device__ inline unsigned cvtpk_bf16(float a, float b) {
  unsigned r;
  asm("v_cvt_pk_bf16_f32 %0, %1, %2" : "=v"(r) : "v"(a), "v"(b));
  return r;
}

// ---- prologue: cast weights fp32 -> bf16 into workspace ----
// dst layout: [768*256] w_qkv_bf16, then [256*256] w_proj_bf16
__global__ void __launch_bounds__(256) wconv_kernel(const float* __restrict__ wqkv,
                                                    const float* __restrict__ wproj,
                                                    short* __restrict__ dst) {
  int i = blockIdx.x * 256 + threadIdx.x;          // 65536 threads, 4 elems each
  float4 v;
  if (i < 49152) v = reinterpret_cast<const float4*>(wqkv)[i];
  else           v = reinterpret_cast<const float4*>(wproj)[i - 49152];
  reinterpret_cast<uint2*>(dst)[i] =
      make_uint2(cvtpk_bf16(v.x, v.y), cvtpk_bf16(v.z, v.w));
}

// ---- fused QKV + windowed attention + proj ----
__global__ void __launch_bounds__(256, 4) attn_kernel(
    const float* __restrict__ x,
    const short* __restrict__ wbf,      // bf16 weights from workspace
    const float* __restrict__ b_qkv,
    const float* __restrict__ b_proj,
    float* __restrict__ out) {

  // LDS: 36864 B total -> 4 blocks/CU (147456 <= 163840)
  __shared__ short sA[32 * 264];        // X tile bf16 (row-major, stride 264); later attn-out tile
  __shared__ short sQK[2 * 32 * 72];    // per-head Q,K rows [token][d], stride 72
  __shared__ short sVT[64 * 72];        // per-head V^T [d][token], token stride 72 (tokens 0..31 used)
  __shared__ short sP[2 * 16 * 24];     // per-attn-wave P tile [q][k], stride 24

  const int tid  = threadIdx.x;
  const int wv   = tid >> 6;            // wave 0..3
  const int lane = tid & 63;
  const int L    = lane & 15;
  const int quad = lane >> 4;           // 0..3
  const int bid  = blockIdx.x;
  // softmax window-select: lane's q-window ((lane>>3)&1) vs which half holds it (lane>>5)
  const bool selw = (((lane >> 5) ^ (lane >> 3)) & 1);

  const float4v fzero = {0.f, 0.f, 0.f, 0.f};

  // ---------- Phase 0: stage X tile (32x256 fp32 -> bf16 LDS) ----------
  // 8 iterations x 256 threads x 4 floats = 8192 floats = the full 32x256 tile.
  const float* xg = x + (size_t)bid * (32 * 256);
  #pragma unroll
  for (int i = 0; i < 8; ++i) {
    int idx = i * 1024 + tid * 4;
    float4 v = *reinterpret_cast<const float4*>(xg + idx);
    int row = idx >> 8;
    int col = idx & 255;
    *reinterpret_cast<uint2*>(&sA[row * 264 + col]) =
        make_uint2(cvtpk_bf16(v.x, v.y), cvtpk_bf16(v.z, v.w));
  }
  __syncthreads();

  float oreg[4][16];                    // attention output per head: [dchunk*4 + reg] (waves 0,1 only)

  #pragma unroll
  for (int h = 0; h < 4; ++h) {
    // ---------- QKV GEMM: wave computes rows 0..31 x head-local cols [wv*48,+48) ----------
    float4v acc[2][3];
    #pragma unroll
    for (int rt = 0; rt < 2; ++rt)
      #pragma unroll
      for (int ct = 0; ct < 3; ++ct) acc[rt][ct] = fzero;

    const short* wb[3];
    int s_[3], d0_[3];
    #pragma unroll
    for (int ct = 0; ct < 3; ++ct) {
      int c0 = wv * 48 + ct * 16;       // head-local col
      int s  = c0 >> 6;                 // 0=q 1=k 2=v
      int d0 = c0 & 63;
      s_[ct] = s; d0_[ct] = d0;
      int wrow0 = s * 256 + h * 64 + d0;                 // row in w_qkv
      wb[ct] = wbf + (size_t)(wrow0 + L) * 256 + quad * 8;
    }

    #pragma unroll
    for (int kk = 0; kk < 8; ++kk) {
      short8 a[2];
      #pragma unroll
      for (int rt = 0; rt < 2; ++rt)
        a[rt] = *reinterpret_cast<const short8*>(&sA[(rt * 16 + L) * 264 + kk * 32 + quad * 8]);
      short8 b[3];
      #pragma unroll
      for (int ct = 0; ct < 3; ++ct)
        b[ct] = *reinterpret_cast<const short8*>(wb[ct] + kk * 32);
      #pragma unroll
      for (int rt = 0; rt < 2; ++rt)
        #pragma unroll
        for (int ct = 0; ct < 3; ++ct)
          acc[rt][ct] = __builtin_amdgcn_mfma_f32_16x16x32_bf16(a[rt], b[ct], acc[rt][ct], 0, 0, 0);
    }

    // epilogue: + bias, scatter to sQK (row-major) / sVT (transposed), packed cvt
    #pragma unroll
    for (int ct = 0; ct < 3; ++ct) {
      int s = s_[ct], d0 = d0_[ct];
      float bias = b_qkv[s * 256 + h * 64 + d0 + L];
      #pragma unroll
      for (int rt = 0; rt < 2; ++rt) {
        int row0 = rt * 16 + quad * 4;                   // token row of v[0]
        float4v v = acc[rt][ct];
        unsigned u01 = cvtpk_bf16(v[0] + bias, v[1] + bias);
        unsigned u23 = cvtpk_bf16(v[2] + bias, v[3] + bias);
        if (s < 2) {
          short* dq = &sQK[s * (32 * 72) + row0 * 72 + d0 + L];
          dq[0]   = (short)u01;
          dq[72]  = (short)(u01 >> 16);
          dq[144] = (short)u23;
          dq[216] = (short)(u23 >> 16);
        } else {
          *reinterpret_cast<uint2*>(&sVT[(d0 + L) * 72 + row0]) =
              make_uint2(u01, u23);
        }
      }
    }
    __syncthreads();

    // ---------- attention: waves 0,1 own tokens [wv*16, wv*16+16) = 2 windows ----------
    if (wv < 2) {
      // Swapped operands: mfma(K, Q) -> S^T: row = local k = quad*4+r, col = local q = L.
      float4v sacc = fzero;
      #pragma unroll
      for (int ks = 0; ks < 2; ++ks) {
        short8 qa = *reinterpret_cast<const short8*>(&sQK[(wv * 16 + L) * 72 + ks * 32 + quad * 8]);
        short8 kb = *reinterpret_cast<const short8*>(&sQK[32 * 72 + (wv * 16 + L) * 72 + ks * 32 + quad * 8]);
        sacc = __builtin_amdgcn_mfma_f32_16x16x32_bf16(kb, qa, sacc, 0, 0, 0);
      }

      // in-register softmax (q = L, k = quad*4+r)
      float sv[4];
      #pragma unroll
      for (int r = 0; r < 4; ++r) {
        int kidx = quad * 4 + r;
        bool valid = ((kidx >> 3) == (L >> 3)) && ((kidx & 7) <= (L & 7));  // same window + causal
        sv[r] = valid ? sacc[r] * 0.125f : -1e30f;
      }
      float mx = fmaxf(fmaxf(sv[0], sv[1]), fmaxf(sv[2], sv[3]));
      mx = fmaxf(mx, __shfl_xor(mx, 16));          // combine quad pairs
      {
        float mo = __shfl_xor(mx, 32);
        if (selw) mx = mo;                          // pick this lane's q-window
      }
      float e[4];
      float sum = 0.f;
      #pragma unroll
      for (int r = 0; r < 4; ++r) { e[r] = __expf(sv[r] - mx); sum += e[r]; }
      sum += __shfl_xor(sum, 16);
      {
        float so = __shfl_xor(sum, 32);
        if (selw) sum = so;
      }
      float rs = __builtin_amdgcn_rcpf(sum);
      short* sPw = &sP[wv * (16 * 24)];
      *reinterpret_cast<uint2*>(&sPw[L * 24 + quad * 4]) =
          make_uint2(cvtpk_bf16(e[0] * rs, e[1] * rs), cvtpk_bf16(e[2] * rs, e[3] * rs));

      // P @ V via 16x16x32 with K zero-padded 16->32 (A=0 for quads 2,3; B token clamped)
      short8 pa = {0, 0, 0, 0, 0, 0, 0, 0};
      if (quad < 2) pa = *reinterpret_cast<const short8*>(&sPw[L * 24 + quad * 8]);
      #pragma unroll
      for (int dc = 0; dc < 4; ++dc) {
        short8 vb = *reinterpret_cast<const short8*>(
            &sVT[(dc * 16 + L) * 72 + wv * 16 + (quad & 1) * 8]);
        float4v o = __builtin_amdgcn_mfma_f32_16x16x32_bf16(pa, vb, fzero, 0, 0, 0);
        #pragma unroll
        for (int r = 0; r < 4; ++r) oreg[h][dc * 4 + r] = o[r];
      }
    }
    if (h != 3) __syncthreads();   // protect sQK/sVT before next head's epilogue writes
    // (h==3: attn-out writes below touch sA only; all sA X-reads were fenced by this
    //  head's post-epilogue barrier; concurrent PV reads touch sVT/sP only.)
  }

  // ---------- write attention output tile into sA (X tile is dead) ----------
  if (wv < 2) {
    #pragma unroll
    for (int h = 0; h < 4; ++h)
      #pragma unroll
      for (int dc = 0; dc < 4; ++dc) {
        unsigned u01 = cvtpk_bf16(oreg[h][dc * 4 + 0], oreg[h][dc * 4 + 1]);
        unsigned u23 = cvtpk_bf16(oreg[h][dc * 4 + 2], oreg[h][dc * 4 + 3]);
        short* dq = &sA[(wv * 16 + quad * 4) * 264 + h * 64 + dc * 16 + L];
        dq[0]       = (short)u01;
        dq[264]     = (short)(u01 >> 16);
        dq[528]     = (short)u23;
        dq[792]     = (short)(u23 >> 16);
      }
  }
  __syncthreads();

  // ---------- proj GEMM: wave computes rows 0..31 x cols [wv*64,+64) ----------
  float4v pacc[2][4];
  #pragma unroll
  for (int rt = 0; rt < 2; ++rt)
    #pragma unroll
    for (int ct = 0; ct < 4; ++ct) pacc[rt][ct] = fzero;

  const short* wp = wbf + 768 * 256;
  const short* wpb[4];
  #pragma unroll
  for (int ct = 0; ct < 4; ++ct)
    wpb[ct] = wp + (size_t)(wv * 64 + ct * 16 + L) * 256 + quad * 8;

  #pragma unroll
  for (int kk = 0; kk < 8; ++kk) {
    short8 a[2];
    #pragma unroll
    for (int rt = 0; rt < 2; ++rt)
      a[rt] = *reinterpret_cast<const short8*>(&sA[(rt * 16 + L) * 264 + kk * 32 + quad * 8]);
    short8 b[4];
    #pragma unroll
    for (int ct = 0; ct < 4; ++ct)
      b[ct] = *reinterpret_cast<const short8*>(wpb[ct] + kk * 32);
    #pragma unroll
    for (int rt = 0; rt < 2; ++rt)
      #pragma unroll
      for (int ct = 0; ct < 4; ++ct)
        pacc[rt][ct] = __builtin_amdgcn_mfma_f32_16x16x32_bf16(a[rt], b[ct], pacc[rt][ct], 0, 0, 0);
  }

  // epilogue: + bias, fp32 store
  float* og = out + (size_t)bid * (32 * 256);
  #pragma unroll
  for (int ct = 0; ct < 4; ++ct) {
    float bias = b_proj[wv * 64 + ct * 16 + L];
    #pragma unroll
    for (int rt = 0; rt < 2; ++rt)
      #pragma unroll
      for (int r = 0; r < 4; ++r)
        og[(rt * 16 + quad * 4 + r) * 256 + wv * 64 + ct * 16 + L] = pacc[rt][ct][r] + bias;
  }
}

extern "C" void kernel_launch(void* const* d_in, const int* in_sizes, int n_in,
                              void* d_out, int out_size, void* d_ws, size_t ws_size,
                              hipStream_t stream) {
  const float* x      = (const float*)d_in[0];
  const float* w_qkv  = (const float*)d_in[1];
  const float* b_qkv  = (const float*)d_in[2];
  const float* w_proj = (const float*)d_in[3];
  const float* b_proj = (const float*)d_in[4];
  float* out = (float*)d_out;
  short* wbf = (short*)d_ws;                      // 524288 B of bf16 weights

  wconv_kernel<<<256, 256, 0, stream>>>(w_qkv, w_proj, wbf);
  attn_kernel<<<4096, 256, 0, stream>>>(x, wbf, b_qkv, b_proj, out);
}

// Round 6
// 427.098 us; speedup vs baseline: 1.0320x; 1.0268x over previous
//
#include <hip/hip_runtime.h>

// Problem constants: B=32, T=4096, C=256, WINDOW=8, HEADS=4, hd=64
// Rows M = B*T = 131072. 32-token tiles -> 4096 blocks, 256 threads (4 waves).
// wave == head: wave h computes QKV for head h into head-private LDS, then does
// head h's attention reading only its own writes -> 3 barriers per block total.
// LDS 77312 B -> 2 blocks/CU.

typedef __attribute__((ext_vector_type(8))) short short8;
typedef __attribute__((ext_vector_type(4))) float float4v;

// Packed fp32x2 -> bf16x2 (RNE) in one instruction.
__device__ inline unsigned cvtpk_bf16(float a, float b) {
  unsigned r;
  asm("v_cvt_pk_bf16_f32 %0, %1, %2" : "=v"(r) : "v"(a), "v"(b));
  return r;
}

// ---- prologue: cast weights fp32 -> bf16 into workspace ----
// dst layout: [768*256] w_qkv_bf16, then [256*256] w_proj_bf16
__global__ void __launch_bounds__(256) wconv_kernel(const float* __restrict__ wqkv,
                                                    const float* __restrict__ wproj,
                                                    short* __restrict__ dst) {
  int i = blockIdx.x * 256 + threadIdx.x;          // 65536 threads, 4 elems each
  float4 v;
  if (i < 49152) v = reinterpret_cast<const float4*>(wqkv)[i];
  else           v = reinterpret_cast<const float4*>(wproj)[i - 49152];
  reinterpret_cast<uint2*>(dst)[i] =
      make_uint2(cvtpk_bf16(v.x, v.y), cvtpk_bf16(v.z, v.w));
}

// ---- fused QKV + windowed attention + proj ----
__global__ void __launch_bounds__(256, 2) attn_kernel(
    const float* __restrict__ x,
    const short* __restrict__ wbf,      // bf16 weights from workspace
    const float* __restrict__ b_qkv,
    const float* __restrict__ b_proj,
    float* __restrict__ out) {

  // LDS: 77312 B total -> 2 blocks/CU (154624 <= 163840)
  __shared__ short sA[32 * 264];        // X tile bf16 (row-major, stride 264); later attn-out tile
  __shared__ short sQK[4][2][32 * 72];  // per-head Q,K rows [token][d], stride 72 (wave-private)
  __shared__ short sVT[4][64 * 40];     // per-head V^T [d][token], token stride 40 (wave-private)
  __shared__ short sP[4][16 * 24];      // per-wave P tile [q][k], stride 24 (wave-private)

  const int tid  = threadIdx.x;
  const int h    = tid >> 6;            // wave index == head 0..3
  const int lane = tid & 63;
  const int L    = lane & 15;
  const int quad = lane >> 4;           // 0..3
  const int bid  = blockIdx.x;
  // softmax window-select: lane's q-window ((lane>>3)&1) vs which half holds it (lane>>5)
  const bool selw = (((lane >> 5) ^ (lane >> 3)) & 1);

  const float4v fzero = {0.f, 0.f, 0.f, 0.f};

  // ---------- Phase 0: stage X tile (32x256 fp32 -> bf16 LDS) ----------
  // 8 iterations x 256 threads x 4 floats = 8192 floats = the full 32x256 tile.
  const float* xg = x + (size_t)bid * (32 * 256);
  #pragma unroll
  for (int i = 0; i < 8; ++i) {
    int idx = i * 1024 + tid * 4;
    float4 v = *reinterpret_cast<const float4*>(xg + idx);
    int row = idx >> 8;
    int col = idx & 255;
    *reinterpret_cast<uint2*>(&sA[row * 264 + col]) =
        make_uint2(cvtpk_bf16(v.x, v.y), cvtpk_bf16(v.z, v.w));
  }
  __syncthreads();                      // barrier 1: sA ready

  // ---------- QKV for head h: 3 parts (s=0 q, 1 k, 2 v), each 32 tok x 64 cols ----------
  #pragma unroll
  for (int s = 0; s < 3; ++s) {
    float4v acc[2][4];
    #pragma unroll
    for (int rt = 0; rt < 2; ++rt)
      #pragma unroll
      for (int ct = 0; ct < 4; ++ct) acc[rt][ct] = fzero;

    // weight rows for this part: wrow = s*256 + h*64 + (ct*16 + L)
    const short* wbase = wbf + (size_t)(s * 256 + h * 64 + L) * 256 + quad * 8;

    #pragma unroll
    for (int kk = 0; kk < 8; ++kk) {
      short8 a[2];
      #pragma unroll
      for (int rt = 0; rt < 2; ++rt)
        a[rt] = *reinterpret_cast<const short8*>(&sA[(rt * 16 + L) * 264 + kk * 32 + quad * 8]);
      short8 b[4];
      #pragma unroll
      for (int ct = 0; ct < 4; ++ct)
        b[ct] = *reinterpret_cast<const short8*>(wbase + ct * 16 * 256 + kk * 32);
      #pragma unroll
      for (int rt = 0; rt < 2; ++rt)
        #pragma unroll
        for (int ct = 0; ct < 4; ++ct)
          acc[rt][ct] = __builtin_amdgcn_mfma_f32_16x16x32_bf16(a[rt], b[ct], acc[rt][ct], 0, 0, 0);
    }

    // epilogue: + bias, scatter to head-private sQK (row-major) / sVT (transposed)
    #pragma unroll
    for (int ct = 0; ct < 4; ++ct) {
      int d0 = ct * 16;
      float bias = b_qkv[s * 256 + h * 64 + d0 + L];
      #pragma unroll
      for (int rt = 0; rt < 2; ++rt) {
        int row0 = rt * 16 + quad * 4;                   // token row of v[0]
        float4v v = acc[rt][ct];
        unsigned u01 = cvtpk_bf16(v[0] + bias, v[1] + bias);
        unsigned u23 = cvtpk_bf16(v[2] + bias, v[3] + bias);
        if (s < 2) {
          short* dq = &sQK[h][s][row0 * 72 + d0 + L];
          dq[0]   = (short)u01;
          dq[72]  = (short)(u01 >> 16);
          dq[144] = (short)u23;
          dq[216] = (short)(u23 >> 16);
        } else {
          *reinterpret_cast<uint2*>(&sVT[h][(d0 + L) * 40 + row0]) =
              make_uint2(u01, u23);
        }
      }
    }
  }

  // Same-wave LDS write->read: DS pipe is in-order per wave; fence stops any
  // compiler reordering and drains lgkm before the dependent reads below.
  asm volatile("s_waitcnt lgkmcnt(0)" ::: "memory");

  // ---------- attention for head h: two 16-token groups (no barriers needed) ----------
  float oreg[2][16];                    // [group][dchunk*4 + reg]
  #pragma unroll
  for (int grp = 0; grp < 2; ++grp) {
    const int tb = grp * 16;
    // Swapped operands: mfma(K, Q) -> S^T: row = local k = quad*4+r, col = local q = L.
    float4v sacc = fzero;
    #pragma unroll
    for (int ks = 0; ks < 2; ++ks) {
      short8 qa = *reinterpret_cast<const short8*>(&sQK[h][0][(tb + L) * 72 + ks * 32 + quad * 8]);
      short8 kb = *reinterpret_cast<const short8*>(&sQK[h][1][(tb + L) * 72 + ks * 32 + quad * 8]);
      sacc = __builtin_amdgcn_mfma_f32_16x16x32_bf16(kb, qa, sacc, 0, 0, 0);
    }

    // in-register softmax (q = L, k = quad*4+r)
    float sv[4];
    #pragma unroll
    for (int r = 0; r < 4; ++r) {
      int kidx = quad * 4 + r;
      bool valid = ((kidx >> 3) == (L >> 3)) && ((kidx & 7) <= (L & 7));  // same window + causal
      sv[r] = valid ? sacc[r] * 0.125f : -1e30f;
    }
    float mx = fmaxf(fmaxf(sv[0], sv[1]), fmaxf(sv[2], sv[3]));
    mx = fmaxf(mx, __shfl_xor(mx, 16));          // combine quad pairs
    {
      float mo = __shfl_xor(mx, 32);
      if (selw) mx = mo;                          // pick this lane's q-window
    }
    float e[4];
    float sum = 0.f;
    #pragma unroll
    for (int r = 0; r < 4; ++r) { e[r] = __expf(sv[r] - mx); sum += e[r]; }
    sum += __shfl_xor(sum, 16);
    {
      float so = __shfl_xor(sum, 32);
      if (selw) sum = so;
    }
    float rs = __builtin_amdgcn_rcpf(sum);
    short* sPw = &sP[h][0];                       // wave-private slot, reused per group
    *reinterpret_cast<uint2*>(&sPw[L * 24 + quad * 4]) =
        make_uint2(cvtpk_bf16(e[0] * rs, e[1] * rs), cvtpk_bf16(e[2] * rs, e[3] * rs));

    // P @ V via 16x16x32 with K zero-padded 16->32 (A=0 for quads 2,3; B token clamped)
    short8 pa = {0, 0, 0, 0, 0, 0, 0, 0};
    if (quad < 2) pa = *reinterpret_cast<const short8*>(&sPw[L * 24 + quad * 8]);
    #pragma unroll
    for (int dc = 0; dc < 4; ++dc) {
      short8 vb = *reinterpret_cast<const short8*>(
          &sVT[h][(dc * 16 + L) * 40 + tb + (quad & 1) * 8]);
      float4v o = __builtin_amdgcn_mfma_f32_16x16x32_bf16(pa, vb, fzero, 0, 0, 0);
      #pragma unroll
      for (int r = 0; r < 4; ++r) oreg[grp][dc * 4 + r] = o[r];
    }
  }

  __syncthreads();   // barrier 2: all waves done reading sA (QKV a-loads) -> safe to overwrite

  // ---------- write attention output tile into sA (X tile is dead) ----------
  #pragma unroll
  for (int grp = 0; grp < 2; ++grp)
    #pragma unroll
    for (int dc = 0; dc < 4; ++dc) {
      unsigned u01 = cvtpk_bf16(oreg[grp][dc * 4 + 0], oreg[grp][dc * 4 + 1]);
      unsigned u23 = cvtpk_bf16(oreg[grp][dc * 4 + 2], oreg[grp][dc * 4 + 3]);
      short* dq = &sA[(grp * 16 + quad * 4) * 264 + h * 64 + dc * 16 + L];
      dq[0]       = (short)u01;
      dq[264]     = (short)(u01 >> 16);
      dq[528]     = (short)u23;
      dq[792]     = (short)(u23 >> 16);
    }
  __syncthreads();   // barrier 3: attn-out tile ready

  // ---------- proj GEMM: wave computes rows 0..31 x cols [h*64,+64) ----------
  float4v pacc[2][4];
  #pragma unroll
  for (int rt = 0; rt < 2; ++rt)
    #pragma unroll
    for (int ct = 0; ct < 4; ++ct) pacc[rt][ct] = fzero;

  const short* wp = wbf + 768 * 256;
  const short* wpb[4];
  #pragma unroll
  for (int ct = 0; ct < 4; ++ct)
    wpb[ct] = wp + (size_t)(h * 64 + ct * 16 + L) * 256 + quad * 8;

  #pragma unroll
  for (int kk = 0; kk < 8; ++kk) {
    short8 a[2];
    #pragma unroll
    for (int rt = 0; rt < 2; ++rt)
      a[rt] = *reinterpret_cast<const short8*>(&sA[(rt * 16 + L) * 264 + kk * 32 + quad * 8]);
    short8 b[4];
    #pragma unroll
    for (int ct = 0; ct < 4; ++ct)
      b[ct] = *reinterpret_cast<const short8*>(wpb[ct] + kk * 32);
    #pragma unroll
    for (int rt = 0; rt < 2; ++rt)
      #pragma unroll
      for (int ct = 0; ct < 4; ++ct)
        pacc[rt][ct] = __builtin_amdgcn_mfma_f32_16x16x32_bf16(a[rt], b[ct], pacc[rt][ct], 0, 0, 0);
  }

  // epilogue: + bias, fp32 store
  float* og = out + (size_t)bid * (32 * 256);
  #pragma unroll
  for (int ct = 0; ct < 4; ++ct) {
    float bias = b_proj[h * 64 + ct * 16 + L];
    #pragma unroll
    for (int rt = 0; rt < 2; ++rt)
      #pragma unroll
      for (int r = 0; r < 4; ++r)
        og[(rt * 16 + quad * 4 + r) * 256 + h * 64 + ct * 16 + L] = pacc[rt][ct][r] + bias;
  }
}

extern "C" void kernel_launch(void* const* d_in, const int* in_sizes, int n_in,
                              void* d_out, int out_size, void* d_ws, size_t ws_size,
                              hipStream_t stream) {
  const float* x      = (const float*)d_in[0];
  const float* w_qkv  = (const float*)d_in[1];
  const float* b_qkv  = (const float*)d_in[2];
  const float* w_proj = (const float*)d_in[3];
  const float* b_proj = (const float*)d_in[4];
  float* out = (float*)d_out;
  short* wbf = (short*)d_ws;                      // 524288 B of bf16 weights

  wconv_kernel<<<256, 256, 0, stream>>>(w_qkv, w_proj, wbf);
  attn_kernel<<<4096, 256, 0, stream>>>(x, wbf, b_qkv, b_proj, out);
}